// Round 3
// 264.136 us; speedup vs baseline: 1.0178x; 1.0178x over previous
//
#include <hip/hip_runtime.h>
#include <cstdint>

#define SEQ 4096
#define NH 12
#define DH 64
#define DM 768
#define MT 8192      // B*SEQ
#define QKVN 2304    // 3*DM

typedef __bf16 bf16;
typedef __attribute__((ext_vector_type(8))) __bf16 bf16x8;
typedef __attribute__((ext_vector_type(4))) __bf16 bf16x4;
typedef __attribute__((ext_vector_type(2))) __bf16 bf16x2;
typedef __attribute__((ext_vector_type(4))) float f32x4;
typedef __attribute__((ext_vector_type(16))) float f32x16;
typedef __attribute__((ext_vector_type(2))) int int2v;

// async global->LDS, 16B per lane. LDS dest is wave-uniform base + lane*16.
__device__ __forceinline__ void async_ld16(const void* g, void* lds) {
  __builtin_amdgcn_global_load_lds(
      (__attribute__((address_space(1))) void*)(void*)g,
      (__attribute__((address_space(3))) void*)lds, 16, 0, 0);
}

// Schraudolph exp2 in the f32-bit domain: bits = (int)(s*2^23 + 16252*65536).
// bits>>16 are the bf16(2^s) bits (same +-3.5% sawtooth as the old bf16-domain
// version, shifted by a constant factor 2^(0.5/128) that is common-mode and
// cancels in the softmax ratio). bits&0xffff0000 reinterpreted as f32 is
// EXACTLY the bf16 P value — so the VALU rowsum matches PV's P bit-for-bit.
__device__ __forceinline__ int sexp2_bits(float s) {
  return (int)__builtin_fmaf(s, 8388608.0f, 1065091072.0f);
}

// pack {lo.hi16, hi.hi16} -> one dword (two bf16 lanes)
__device__ __forceinline__ int pack_hi16(int lo, int hi) {
#if __has_builtin(__builtin_amdgcn_perm)
  return (int)__builtin_amdgcn_perm((unsigned)hi, (unsigned)lo, 0x07060302u);
#else
  return (int)(((unsigned)lo >> 16) | ((unsigned)hi & 0xffff0000u));
#endif
}

// (a,b) -> a' = {a.lo32, b.lo32}, b' = {a.hi32, b.hi32}
__device__ __forceinline__ void lane32_swap(int& a, int& b) {
#if __has_builtin(__builtin_amdgcn_permlane32_swap)
  int2v r = __builtin_amdgcn_permlane32_swap(a, b, false, false);
  a = r.x; b = r.y;
#else
  int hi = (threadIdx.x & 63) >> 5;
  int ra = __shfl_xor(a, 32, 64), rb = __shfl_xor(b, 32, 64);
  int na = hi ? rb : a;
  int nb = hi ? b : ra;
  a = na; b = nb;
#endif
}

// ---------------------------------------------------------------- converts (merged)
#define NX4  (MT * DM / 4)
#define NW14 (QKVN * DM / 4)
#define NW24 (DM * DM / 4)
__global__ void cvt_all(const float* __restrict__ x, const float* __restrict__ w1,
                        const float* __restrict__ w2, bf16* __restrict__ xb,
                        bf16* __restrict__ wb1, bf16* __restrict__ wb2) {
  int i = blockIdx.x * blockDim.x + threadIdx.x;
  const float* src; bf16* dst; int j;
  if (i < NX4) { src = x; dst = xb; j = i; }
  else if (i < NX4 + NW14) { src = w1; dst = wb1; j = i - NX4; }
  else if (i < NX4 + NW14 + NW24) { src = w2; dst = wb2; j = i - NX4 - NW14; }
  else return;
  f32x4 v = ((const f32x4*)src)[j];
  bf16x4 o;
  o.x = (bf16)v.x; o.y = (bf16)v.y; o.z = (bf16)v.z; o.w = (bf16)v.w;
  ((bf16x4*)dst)[j] = o;
}

// ---------------------------------------------------------------- GEMM (B^T)
// C[M,N] = A[M,K] @ Bw[N,K]^T. 128x128 tile, BK=64 (R15: halves barrier drains,
// 24->12 iters at K=768; 32 MFMAs per staging round). 4 waves, 64x64/wave.
// 128B LDS rows would 16-way-conflict fragment b128 reads, so the 16B granule is
// XOR-swizzled on the GLOBAL side (pg = (lane&7)^(lane>>3)); fragment reads use
// g = G ^ (row&7) -> 8 accesses/bank per b128 (hardware minimum, conflict-free).
// V^T bounce buffer sT ALIASES sA/sB (only live after the K-loop's last barrier)
// so MODE-0 LDS stays 32 KB. 1-D grid, grouped swizzle (R10-verified).
// MODE 0: QKV epilogue -> +bias, Q(*0.125*log2e)/K as [bh][n][d]; V^T -> [bh][d][n]
// MODE 1: out-proj epilogue -> +bias, fp32 row-major [M,N]
template<int MODE>
__global__ __launch_bounds__(256) void gemm_bt(
    const bf16* __restrict__ A, const bf16* __restrict__ Bw,
    const float* __restrict__ bias,
    bf16* __restrict__ outQ, bf16* __restrict__ outK, bf16* __restrict__ outVt,
    float* __restrict__ outF,
    int M, int N, int K)
{
  __shared__ bf16 smem[2 * 128 * 64];   // sA | sB ; sT aliases the front 17.4 KB
  bf16* sA = smem;
  bf16* sB = smem + 128 * 64;
  bf16* sT = smem;                      // reused only after the final K-loop barrier

  const int tid  = threadIdx.x;
  const int wave = tid >> 6;
  const int lane = tid & 63;
  const int l15  = lane & 15;
  const int quad = lane >> 4;

  constexpr int NT = (MODE == 0) ? (QKVN / 128) : (DM / 128);
  const int lin = blockIdx.x;
  const int rem = lin % (NT * 8);
  const int m0 = ((lin / (NT * 8)) * 8 + (rem % 8)) * 128;
  const int n0 = (rem / 8) * 128;

  const int rowbase = (wave >> 1) * 64;
  const int colbase = (wave & 1) * 64;

  f32x4 acc[4][4] = {};

  const int srow = lane >> 3;            // row within 8-row chunk
  const int spg  = (lane & 7) ^ srow;    // swizzled 16B granule within 128B row
  const int xk   = l15 & 7;              // fragment-read swizzle key

  for (int kt = 0; kt < K; kt += 64) {
    // 32 chunks of 1KB (8 rows x 64 bf16): 16 for A, 16 for B; chunk = p*4+wave
#pragma unroll
    for (int p = 0; p < 8; ++p) {
      int chunk = p * 4 + wave;
      if (chunk < 16) {
        int row = chunk * 8 + srow;
        async_ld16(A + (size_t)(m0 + row) * K + kt + spg * 8, &sA[chunk * 512]);
      } else {
        int row = (chunk - 16) * 8 + srow;
        async_ld16(Bw + (size_t)(n0 + row) * K + kt + spg * 8, &sB[(chunk - 16) * 512]);
      }
    }
    __syncthreads();

#pragma unroll
    for (int ks = 0; ks < 2; ++ks) {
      bf16x8 af[4], bfr[4];
#pragma unroll
      for (int rt = 0; rt < 4; ++rt)
        af[rt] = *(const bf16x8*)&sA[(rowbase + rt * 16 + l15) * 64 +
                                     (((ks * 4 + quad) ^ xk) * 8)];
#pragma unroll
      for (int ct = 0; ct < 4; ++ct)
        bfr[ct] = *(const bf16x8*)&sB[(colbase + ct * 16 + l15) * 64 +
                                      (((ks * 4 + quad) ^ xk) * 8)];
#pragma unroll
      for (int rt = 0; rt < 4; ++rt)
#pragma unroll
        for (int ct = 0; ct < 4; ++ct)
          acc[rt][ct] = __builtin_amdgcn_mfma_f32_16x16x32_bf16(af[rt], bfr[ct], acc[rt][ct], 0, 0, 0);
    }
    __syncthreads();
  }

  if (MODE == 0) {
    const int g = n0 / DM;                       // uniform per block (0=q,1=k,2=v)
    if (g < 2) {
      const float qscale = 0.125f * 1.4426950408889634f;  // fold /8 and log2(e)
#pragma unroll
      for (int ct = 0; ct < 4; ++ct) {
        int j = n0 + colbase + ct * 16 + l15;
        float bj = bias[j];
        int f = j % DM;
        int h = f >> 6, d = f & 63;
#pragma unroll
        for (int rt = 0; rt < 4; ++rt) {
          int mrow = m0 + rowbase + rt * 16 + quad * 4;
#pragma unroll
          for (int r = 0; r < 4; ++r) {
            float v = acc[rt][ct][r] + bj;
            int m = mrow + r;
            int b = m >> 12, n = m & 4095;
            int bh = b * NH + h;
            if (g == 0) outQ[((size_t)bh * SEQ + n) * DH + d] = (bf16)(v * qscale);
            else        outK[((size_t)bh * SEQ + n) * DH + d] = (bf16)v;
          }
        }
      }
    } else {
      // V block: bounce through LDS (sT aliases sA/sB — safe after barrier),
      // store V^T coalesced along n
      const int f0 = n0 - 2 * DM;
      const int b = m0 >> 12, n0m = m0 & 4095;
#pragma unroll
      for (int p = 0; p < 2; ++p) {
        __syncthreads();
        if (colbase == p * 64) {
#pragma unroll
          for (int ct = 0; ct < 4; ++ct) {
            int jl = ct * 16 + l15;
            float bj = bias[n0 + p * 64 + jl];
#pragma unroll
            for (int rt = 0; rt < 4; ++rt) {
              int ml = rowbase + rt * 16 + quad * 4;
#pragma unroll
              for (int r = 0; r < 4; ++r)
                sT[jl * 136 + ml + r] = (bf16)(acc[rt][ct][r] + bj);
            }
          }
        }
        __syncthreads();
#pragma unroll
        for (int p2 = 0; p2 < 4; ++p2) {
          int slot = p2 * 256 + tid;
          int jr = slot >> 4, mc = (slot & 15) * 8;
          int fj = f0 + p * 64 + jr;
          int h = fj >> 6, d = fj & 63;
          *(bf16x8*)&outVt[((size_t)(b * NH + h) * DH + d) * SEQ + n0m + mc] =
              *(const bf16x8*)&sT[jr * 136 + mc];
        }
      }
    }
  } else {
#pragma unroll
    for (int ct = 0; ct < 4; ++ct) {
      int j = n0 + colbase + ct * 16 + l15;
      float bj = bias[j];
#pragma unroll
      for (int rt = 0; rt < 4; ++rt) {
        int mrow = m0 + rowbase + rt * 16 + quad * 4;
#pragma unroll
        for (int r = 0; r < 4; ++r)
          outF[(size_t)(mrow + r) * N + j] = acc[rt][ct][r] + bj;
      }
    }
  }
}

// ---------------------------------------------------------------- flash attention v15
// R16 (resubmitted R17/R18 after broker timeouts): attack the latency bind.
// Counters showed per-pipe MFMA/VALU busy ~10-12% (the 46/48% figures are
// 4-pipe aggregates), occupancy 27% ~= 2 blocks/CU of the 3 the grid offers ->
// register-residency cap. Changes:
//  (a) drop o2 ones-column MFMA + zc + ones1 (36 unified VGPRs): rowsum now on
//      the VALU in the f32-bit Schraudolph domain (bits&0xffff0000 == exact bf16
//      P value, so the sum matches PV bit-for-bit); __launch_bounds__(256,3)
//      pins the allocator at 3 waves/EU.
//  (b) XCD swizzle: each bh's 32 q-blocks -> one XCD, so K/V (2 MB/bh) stays
//      L2-resident per XCD instead of all 24 bh streaming through every L2.
__global__ __launch_bounds__(256, 3) void flash_attn(
    const bf16* __restrict__ Q, const bf16* __restrict__ Kg,
    const bf16* __restrict__ Vt, bf16* __restrict__ Oout)
{
  __shared__ bf16 sK[2][64 * 64];    // [key][d], granule-swizzled
  __shared__ bf16 sV[2][64 * 64];    // [d][key], granule-swizzled

  // XCD-aware remap: linear wg id L round-robins across 8 XCDs (xcd = L%8).
  // Give xcd X the heads {X, X+8, X+16}; 32 q-blocks per head stay on one XCD.
  const int L    = blockIdx.x + (SEQ / 128) * blockIdx.y;   // 0..767
  const int xcd  = L & 7;
  const int slot = L >> 3;                                  // 0..95
  const int bh   = xcd + 8 * (slot >> 5);                   // 0..23
  const int qb   = slot & 31;

  {
    int ph = (qb + bh) & 3;
    if (ph == 1) __builtin_amdgcn_s_sleep(2);
    else if (ph == 2) __builtin_amdgcn_s_sleep(4);
    else if (ph == 3) __builtin_amdgcn_s_sleep(6);
  }

  const int tid  = threadIdx.x;
  const int wave = tid >> 6;
  const int lane = tid & 63;
  const int l31  = lane & 31;
  const int hi   = lane >> 5;
  const int q0w = qb * 128 + wave * 32;

  const bf16* Qb = Q  + (size_t)bh * SEQ * DH;
  const bf16* Kb = Kg + (size_t)bh * SEQ * DH;
  const bf16* Vb = Vt + (size_t)bh * DH * SEQ;

  const int srow = lane >> 3;
  const int spg  = lane & 7;

  bf16x8 qf[4];
#pragma unroll
  for (int dc = 0; dc < 4; ++dc)
    qf[dc] = *(const bf16x8*)&Qb[(size_t)(q0w + l31) * DH + dc * 16 + hi * 8];

  f32x16 o0 = {}, o1 = {};
  float rs0 = 0.f, rs1 = 0.f, rs2 = 0.f, rs3 = 0.f;   // f32 rowsum accumulators

  const int keyk = (l31 & 7) ^ (((l31 >> 3) & 3) << 1);
  int off[4];                       // shared K/V fragment offsets (identical maps)
#pragma unroll
  for (int dc = 0; dc < 4; ++dc)
    off[dc] = l31 * 64 + (((dc * 2 + hi) ^ keyk) * 8);

  auto stage = [&](int kt, int buf) {
#pragma unroll
    for (int j = 0; j < 2; ++j) {
      int r0 = wave * 16 + j * 8;
      int row = r0 + srow;
      int lg = spg ^ (row & 7) ^ (((row >> 3) & 3) << 1);
      async_ld16(Kb + (size_t)(kt + row) * DH + lg * 8, &sK[buf][r0 * 64]);
      async_ld16(Vb + (size_t)row * SEQ + kt + lg * 8, &sV[buf][r0 * 64]);
    }
  };

  auto compute = [&](const bf16* sKp, const bf16* sVp) {
#pragma unroll
    for (int kb = 0; kb < 2; ++kb) {
      f32x16 s = {};
#pragma unroll
      for (int dc = 0; dc < 4; ++dc) {
        bf16x8 kf = *(const bf16x8*)&sKp[off[dc] + kb * 2048];
        s = __builtin_amdgcn_mfma_f32_32x32x16_bf16(kf, qf[dc], s, 0, 0, 0);
      }
#pragma unroll
      for (int kc = 0; kc < 2; ++kc) {
        int b0 = sexp2_bits(s[8 * kc + 0]);
        int b1 = sexp2_bits(s[8 * kc + 1]);
        int b2 = sexp2_bits(s[8 * kc + 2]);
        int b3 = sexp2_bits(s[8 * kc + 3]);
        int b4 = sexp2_bits(s[8 * kc + 4]);
        int b5 = sexp2_bits(s[8 * kc + 5]);
        int b6 = sexp2_bits(s[8 * kc + 6]);
        int b7 = sexp2_bits(s[8 * kc + 7]);
        // rowsum of the EXACT bf16 P values (hi16 reinterpreted as f32)
        rs0 += __int_as_float(b0 & 0xffff0000) + __int_as_float(b4 & 0xffff0000);
        rs1 += __int_as_float(b1 & 0xffff0000) + __int_as_float(b5 & 0xffff0000);
        rs2 += __int_as_float(b2 & 0xffff0000) + __int_as_float(b6 & 0xffff0000);
        rs3 += __int_as_float(b3 & 0xffff0000) + __int_as_float(b7 & 0xffff0000);
        int g0a = pack_hi16(b0, b1);
        int g0b = pack_hi16(b2, b3);
        int g1a = pack_hi16(b4, b5);
        int g1b = pack_hi16(b6, b7);
        lane32_swap(g0a, g1a);
        lane32_swap(g0b, g1b);
        union { int i[4]; bf16x8 v; } Af;
        Af.i[0] = g0a; Af.i[1] = g0b; Af.i[2] = g1a; Af.i[3] = g1b;
        bf16x8 vf0 = *(const bf16x8*)&sVp[off[kb * 2 + kc]];
        bf16x8 vf1 = *(const bf16x8*)&sVp[off[kb * 2 + kc] + 2048];
        o0 = __builtin_amdgcn_mfma_f32_32x32x16_bf16(Af.v, vf0, o0, 0, 0, 0);
        o1 = __builtin_amdgcn_mfma_f32_32x32x16_bf16(Af.v, vf1, o1, 0, 0, 0);
      }
    }
  };

  stage(0, 0);
  __syncthreads();

  for (int kt = 0; kt < SEQ; kt += 128) {
    if (kt + 64 < SEQ) stage(kt + 64, 1);
    compute(sK[0], sV[0]);
    __syncthreads();
    if (kt + 128 < SEQ) stage(kt + 128, 0);
    compute(sK[1], sV[1]);
    __syncthreads();
  }

  // lane l holds the partial rowsum for q = l&31 over its hi-parity key subset;
  // the complementary subset lives on lane l^32.
  float rsum = (rs0 + rs1) + (rs2 + rs3);
  rsum += __shfl_xor(rsum, 32, 64);
  float invq = 1.0f / rsum;          // lane l: 1/sum for q-row (l&31)

  const int bg = bh / NH, h = bh % NH;
#pragma unroll
  for (int i = 0; i < 16; ++i) {
    int ql = 8 * (i >> 2) + (i & 3) + 4 * hi;
    float inv = __shfl(invq, ql, 64);          // bpermute from lane ql
    size_t base = (size_t)(bg * SEQ + q0w + ql) * DM + h * DH;
    Oout[base + l31]      = (bf16)(o0[i] * inv);
    Oout[base + 32 + l31] = (bf16)(o1[i] * inv);
  }
}

// ---------------------------------------------------------------- launcher
extern "C" void kernel_launch(void* const* d_in, const int* in_sizes, int n_in,
                              void* d_out, int out_size, void* d_ws, size_t ws_size,
                              hipStream_t stream) {
  const float* x     = (const float*)d_in[0];
  const float* qkv_w = (const float*)d_in[1];
  const float* qkv_b = (const float*)d_in[2];
  const float* out_w = (const float*)d_in[3];
  const float* out_b = (const float*)d_in[4];
  float* out = (float*)d_out;

  char* w = (char*)d_ws;
  bf16* xb    = (bf16*)w; w += (size_t)MT * DM * 2;
  bf16* wqkv  = (bf16*)w; w += (size_t)QKVN * DM * 2;
  bf16* wout  = (bf16*)w; w += (size_t)DM * DM * 2;
  bf16* Qw    = (bf16*)w; w += (size_t)MT * DM * 2;        // [bh][n][d], scaled 0.125*log2e
  bf16* Kw    = (bf16*)w; w += (size_t)MT * DM * 2;        // [bh][n][d]
  bf16* Vtw   = (bf16*)w; w += (size_t)MT * DM * 2;        // [bh][d][n]
  bf16* attnV = (bf16*)w; w += (size_t)MT * DM * 2;        // [m][768]

  const int tot4 = NX4 + NW14 + NW24;
  cvt_all<<<dim3((tot4 + 255) / 256), 256, 0, stream>>>(x, qkv_w, out_w, xb, wqkv, wout);

  gemm_bt<0><<<dim3((QKVN / 128) * (MT / 128)), 256, 0, stream>>>(
      xb, wqkv, qkv_b, Qw, Kw, Vtw, nullptr, MT, QKVN, DM);

  flash_attn<<<dim3(SEQ / 128, 2 * NH), 256, 0, stream>>>(Qw, Kw, Vtw, attnV);

  gemm_bt<1><<<dim3((DM / 128) * (MT / 128)), 256, 0, stream>>>(
      attnV, wout, out_b, nullptr, nullptr, nullptr, out, MT, DM, DM);
}